// Round 1
// 73.586 us; speedup vs baseline: 1.1053x; 1.1053x over previous
//
#include <hip/hip_runtime.h>

#define Gn    32
#define NVn   64
#define Hn    256
#define OT    32            // o-tile width per block
#define ZPAD  264           // 256 + 8 bf16 pad (b128-aligned rows, spread banks)
#define EPAD  34            // ey LDS row pad (floats)

typedef __attribute__((ext_vector_type(8))) short  bf16x8;
typedef __attribute__((ext_vector_type(4))) float  f32x4;

__device__ inline unsigned short f2bf(float f) {
    unsigned int u = __builtin_bit_cast(unsigned int, f);
    return (unsigned short)((u + 0x7FFFu + ((u >> 16) & 1u)) >> 16);
}

// ---------------------------------------------------------------------------
// Single fused kernel. Block = (g, o-tile of 32). 512 threads (8 waves).
// Phase 1: stage z[g] (64x256) and Wc/Wy o-tile rows (2x32x256) fp32->bf16
//          into LDS (one barrier; LDS read-only afterwards).
// Phase 2: dual GEMM via mfma_f32_16x16x32_bf16. Wave w owns n-strip (w&3)
//          x o-half (w>>2) of BOTH c and y tiles: 8 K-chunks x 2 MFMA.
//          Fragment maps (m89-verified): A/B row=lane&15, k=quad*8+j;
//          C/D col=lane&15, row=quad*4+r.
// Phase 3: ec=exp(-(c+bc)) kept in registers; ey=exp(-(y+by)) -> LDS tile.
// Phase 4: out[g,i,o] = (1/cnt) * sum_{j active} rcp(1 + ec[i,o]*ey[j,o]).
//          Active-j indices compacted via wave-0 ballot (unguarded j-loop).
// No workspace: ec/ey never touch global memory.
// ---------------------------------------------------------------------------
__global__ __launch_bounds__(512) void fused_attn(
    const float* __restrict__ z,  const float* __restrict__ mask,
    const float* __restrict__ Wc, const float* __restrict__ bc,
    const float* __restrict__ Wy, const float* __restrict__ by,
    float* __restrict__ out)
{
    // Bijective XCD swizzle: 256 blocks / 8 XCDs -> XCD x gets logical ids
    // [x*32, x*32+32) = 4 whole graphs incl. all their o-tiles (z L2 reuse).
    const int phys = blockIdx.x;
    const int lid  = (phys & 7) * 32 + (phys >> 3);
    const int g    = lid >> 3;
    const int o0   = (lid & 7) * OT;

    __shared__ __align__(16) unsigned short Zs[NVn][ZPAD];     // z[g] bf16
    __shared__ __align__(16) unsigned short Wsh[2 * OT][ZPAD]; // rows 0..31 Wc, 32..63 Wy
    __shared__ float eyL[NVn][EPAD];
    __shared__ float mskL[NVn];
    __shared__ int   act[NVn];
    __shared__ int   cnt_s;

    const int t = threadIdx.x;

    // ---- mask compaction (wave 0 only) ----
    if (t < 64) {
        const float m = mask[g * NVn + t];
        mskL[t] = m;
        const unsigned long long b = __ballot(m != 0.f);
        const int below = __popcll(b & ((1ull << t) - 1ull));
        if (m != 0.f) act[below] = t;
        if (t == 0) cnt_s = (int)__popcll(b);
    }

    // ---- Phase 1: stage Z and W tiles (issue all 16 loads, then convert) ----
    const float* zg = z + (size_t)g * NVn * Hn;
    float4 za[4], zb[4], wa[4], wb[4];
#pragma unroll
    for (int c = 0; c < 4; ++c) {
        const int idx = t + c * 512;           // 0..2047
        const int row = idx >> 5;              // 0..63
        const int k8  = (idx & 31) * 8;        // 0,8,..,248
        const float* s = zg + (size_t)row * Hn + k8;
        za[c] = *(const float4*)(s);
        zb[c] = *(const float4*)(s + 4);
    }
#pragma unroll
    for (int c = 0; c < 4; ++c) {
        const int idx = t + c * 512;
        const int row = idx >> 5;
        const int k8  = (idx & 31) * 8;
        const float* s = (row < OT) ? (Wc + (size_t)(o0 + row) * Hn + k8)
                                    : (Wy + (size_t)(o0 + row - OT) * Hn + k8);
        wa[c] = *(const float4*)(s);
        wb[c] = *(const float4*)(s + 4);
    }
#pragma unroll
    for (int c = 0; c < 4; ++c) {
        const int idx = t + c * 512;
        const int row = idx >> 5;
        const int k8  = (idx & 31) * 8;
        bf16x8 v;
        v[0] = (short)f2bf(za[c].x); v[1] = (short)f2bf(za[c].y);
        v[2] = (short)f2bf(za[c].z); v[3] = (short)f2bf(za[c].w);
        v[4] = (short)f2bf(zb[c].x); v[5] = (short)f2bf(zb[c].y);
        v[6] = (short)f2bf(zb[c].z); v[7] = (short)f2bf(zb[c].w);
        *(bf16x8*)&Zs[row][k8] = v;
        bf16x8 w;
        w[0] = (short)f2bf(wa[c].x); w[1] = (short)f2bf(wa[c].y);
        w[2] = (short)f2bf(wa[c].z); w[3] = (short)f2bf(wa[c].w);
        w[4] = (short)f2bf(wb[c].x); w[5] = (short)f2bf(wb[c].y);
        w[6] = (short)f2bf(wb[c].z); w[7] = (short)f2bf(wb[c].w);
        *(bf16x8*)&Wsh[row][k8] = w;
    }
    __syncthreads();

    // ---- Phase 2: dual GEMM ----
    const int wv = t >> 6;
    const int l  = t & 63;
    const int lm = l & 15;
    const int lq = l >> 4;
    const int ns = (wv & 3) * 16;      // n-strip
    const int oh = (wv >> 2) * 16;     // o-half within tile

    f32x4 accC = {0.f, 0.f, 0.f, 0.f};
    f32x4 accY = {0.f, 0.f, 0.f, 0.f};
#pragma unroll
    for (int kk = 0; kk < 8; ++kk) {
        const bf16x8 af  = *(const bf16x8*)&Zs[ns + lm][kk * 32 + lq * 8];
        const bf16x8 bcf = *(const bf16x8*)&Wsh[oh + lm][kk * 32 + lq * 8];
        const bf16x8 byf = *(const bf16x8*)&Wsh[OT + oh + lm][kk * 32 + lq * 8];
        accC = __builtin_amdgcn_mfma_f32_16x16x32_bf16(af, bcf, accC, 0, 0, 0);
        accY = __builtin_amdgcn_mfma_f32_16x16x32_bf16(af, byf, accY, 0, 0, 0);
    }

    // ---- Phase 3: exp epilogue; ec in regs, ey -> LDS ----
    const int o_loc = oh + lm;         // 0..31
    const int o     = o0 + o_loc;
    const float bcv = bc[o];
    const float byv = by[o];
    float ecv[4];
#pragma unroll
    for (int r = 0; r < 4; ++r) {
        ecv[r] = __expf(-(accC[r] + bcv));
        eyL[ns + lq * 4 + r][o_loc] = __expf(-(accY[r] + byv));
    }
    __syncthreads();

    // ---- Phase 4: masked pair reduction ----
    const int cnt = cnt_s;
    float a0 = 0.f, a1 = 0.f, a2 = 0.f, a3 = 0.f;
#pragma unroll 4
    for (int jj = 0; jj < cnt; ++jj) {
        const float ev = eyL[act[jj]][o_loc];
        a0 += __builtin_amdgcn_rcpf(__builtin_fmaf(ecv[0], ev, 1.f));
        a1 += __builtin_amdgcn_rcpf(__builtin_fmaf(ecv[1], ev, 1.f));
        a2 += __builtin_amdgcn_rcpf(__builtin_fmaf(ecv[2], ev, 1.f));
        a3 += __builtin_amdgcn_rcpf(__builtin_fmaf(ecv[3], ev, 1.f));
    }
    const float inv = 1.f / (float)cnt;   // m in {0,1} -> denom = popcount
    float* og = out + (size_t)g * NVn * Hn + o;
    const float s0 = a0 * inv, s1 = a1 * inv, s2 = a2 * inv, s3 = a3 * inv;
    const float sv[4] = {s0, s1, s2, s3};
#pragma unroll
    for (int r = 0; r < 4; ++r) {
        const int i = ns + lq * 4 + r;
        og[(size_t)i * Hn] = (mskL[i] == 0.f) ? 0.f : sv[r];
    }
}

extern "C" void kernel_launch(void* const* d_in, const int* in_sizes, int n_in,
                              void* d_out, int out_size, void* d_ws, size_t ws_size,
                              hipStream_t stream) {
    // inputs: 0=num_graphs, 1=nv, 2=z, 3=mask, 4=Wc, 5=bc, 6=Wy, 7=by
    const float* z    = (const float*)d_in[2];
    const float* mask = (const float*)d_in[3];
    const float* Wc   = (const float*)d_in[4];
    const float* bc   = (const float*)d_in[5];
    const float* Wy   = (const float*)d_in[6];
    const float* by   = (const float*)d_in[7];
    float* out = (float*)d_out;
    (void)d_ws; (void)ws_size;   // no workspace: fully fused

    fused_attn<<<dim3(Gn * (Hn / OT)), 512, 0, stream>>>(z, mask, Wc, bc, Wy, by, out);
}